// Round 10
// baseline (250.447 us; speedup 1.0000x reference)
//
#include <hip/hip_runtime.h>

// TensorizedAutoencoder: B=2048, D=512, H=128, K=16, f32 in/out.
// R10: ONE kernel, ZERO workspace. Grid 256 = (chunk 16 x cluster 16);
// block (c,k): locally assign its 128-row chunk (bit-identical per-row math
// to the passing assign_k: same lane split, same butterfly, same k order),
// thread-0 compact rows with idx==k, then the proven R8 MFMA tile body per
// 16-row tile (weights pipelined in 4-kstep reg batches). Assignment is 16x
// redundant (~2 MFLOP/block) but kills the 2nd graph node, the inter-kernel
// barrier, and all idx/xcf traffic. bid=c*16+k -> cluster k's blocks all on
// XCD k%8: weights HBM-fetched once, L2-served after.
// A-operands hi+lo bf16 split; weights bf16 RNE via v_cvt_pk_bf16_f32.
// D-layout per m89: col=l&15, row=4g+reg.

#define BB 2048
#define DD 512
#define HH 128
#define KK 16
#define CHUNK 128
#define NCHUNK (BB / CHUNK)   // 16

typedef float f4v __attribute__((ext_vector_type(4)));
typedef short s8v __attribute__((ext_vector_type(8)));

union U4 { uint4 u; int4 i; s8v v; };

__device__ inline uint pk2(float a, float b) {   // {bf16(a), bf16(b)} packed
    uint r;
    asm("v_cvt_pk_bf16_f32 %0, %1, %2" : "=v"(r) : "v"(a), "v"(b));
    return r;
}
__device__ inline void split2(float a, float b, uint& hi, uint& lo) {
    hi = pk2(a, b);
    const float ha = __uint_as_float(hi << 16);
    const float hb = __uint_as_float(hi & 0xffff0000u);
    lo = pk2(a - ha, b - hb);                    // residual: split self-corrects
}
__device__ inline U4 packrow(const float* bl) {
    U4 r;
    r.u = make_uint4(pk2(bl[0], bl[1]), pk2(bl[2], bl[3]),
                     pk2(bl[4], bl[5]), pk2(bl[6], bl[7]));
    return r;
}

// ---- enc weight pipeline helpers (static indexing only) ----
__device__ inline void enc_issue(const float* __restrict__ Wp, int b0, int g,
                                 float bl[32]) {
    #pragma unroll
    for (int s4 = 0; s4 < 4; ++s4)
        #pragma unroll
        for (int j = 0; j < 8; ++j)
            bl[s4 * 8 + j] = Wp[(size_t)((b0 + s4) * 32 + g * 8 + j) * HH];
}
__device__ inline void enc_step(const int4* __restrict__ Ah,
                                const int4* __restrict__ Al, int l, int b0,
                                const float bl[32], f4v& aH, f4v& aL) {
    #pragma unroll
    for (int s4 = 0; s4 < 4; ++s4) {
        const U4 bf = packrow(&bl[s4 * 8]);
        U4 ah, al;
        ah.i = Ah[(b0 + s4) * 64 + l];
        al.i = Al[(b0 + s4) * 64 + l];
        aH = __builtin_amdgcn_mfma_f32_16x16x32_bf16(ah.v, bf.v, aH, 0, 0, 0);
        aL = __builtin_amdgcn_mfma_f32_16x16x32_bf16(al.v, bf.v, aL, 0, 0, 0);
    }
}
// ---- dec weight pipeline helpers (batch = kstep s, 4 f-frags) ----
__device__ inline void dec_issue(const float* __restrict__ Vp, int s, int g,
                                 float cl[32]) {
    #pragma unroll
    for (int f = 0; f < 4; ++f)
        #pragma unroll
        for (int j = 0; j < 8; ++j)
            cl[f * 8 + j] = Vp[(size_t)(s * 32 + g * 8 + j) * DD + f * 16];
}
__device__ inline void dec_step(const int4* __restrict__ Dh,
                                const int4* __restrict__ Dl, int l, int s,
                                const float cl[32], f4v dH[4], f4v dL[4]) {
    U4 ah, al;
    ah.i = Dh[s * 64 + l];
    al.i = Dl[s * 64 + l];
    #pragma unroll
    for (int f = 0; f < 4; ++f) {
        const U4 cf = packrow(&cl[f * 8]);
        dH[f] = __builtin_amdgcn_mfma_f32_16x16x32_bf16(ah.v, cf.v, dH[f], 0, 0, 0);
        dL[f] = __builtin_amdgcn_mfma_f32_16x16x32_bf16(al.v, cf.v, dL[f], 0, 0, 0);
    }
}

// Fragment conventions (mfma_f32_16x16x32_bf16, lane l, g=l>>4):
//   A: row=l&15, k=8g+j   B: k=8g+j, col=l&15   D: col=l&15, row=4g+reg [m89]
__global__ __launch_bounds__(512) void ae1_k(const float* __restrict__ x,
                                             const float* __restrict__ c,
                                             const float* __restrict__ encW,
                                             const float* __restrict__ encB,
                                             const float* __restrict__ decW,
                                             const float* __restrict__ decB,
                                             float* __restrict__ out) {
    __shared__ int4 frag[2048];          // 32 KB: enc A / dec A frags
    __shared__ float e_s[16][132];       // 8.25 KB
    __shared__ int asg_s[CHUNK];         // chunk assignments
    __shared__ int ls_s[CHUNK];          // compacted row list for cluster km
    __shared__ int rs_s[16];             // current tile's rows
    __shared__ int cnt_s;

    const int bid = blockIdx.x;
    const int km = bid & (KK - 1);       // cluster (same-km blocks -> same XCD)
    const int r0 = (bid >> 4) * CHUNK;   // chunk base row
    const int tid = threadIdx.x;
    const int w = tid >> 6, l = tid & 63;
    const int r16 = l & 15, g = l >> 4;

    // ---- phase A: exact-f32 assignment of this chunk (wave w: 16 rows) ----
    // Per-row math bit-identical to the passing assign_k (lane split over
    // dims, same FMA order, same 64-lane butterfly, strict < first-min).
    for (int i = 0; i < 16; ++i) {
        const int row = r0 + (w << 4) + i;
        const float4* x4 = reinterpret_cast<const float4*>(x + (size_t)row * DD);
        const float4 xa = x4[l * 2];
        const float4 xb = x4[l * 2 + 1];
        float bestd = 3.4e38f;
        int bestk = 0;
        for (int k = 0; k < KK; ++k) {
            const float4* c4 = reinterpret_cast<const float4*>(c + (size_t)k * DD);
            const float4 ca = c4[l * 2];
            const float4 cb = c4[l * 2 + 1];
            float dotv = xa.x * ca.x + xa.y * ca.y + xa.z * ca.z + xa.w * ca.w
                       + xb.x * cb.x + xb.y * cb.y + xb.z * cb.z + xb.w * cb.w;
            float cc = ca.x * ca.x + ca.y * ca.y + ca.z * ca.z + ca.w * ca.w
                     + cb.x * cb.x + cb.y * cb.y + cb.z * cb.z + cb.w * cb.w;
            float v = cc - 2.0f * dotv;  // ||x||^2 constant across k (argmin-inv)
            #pragma unroll
            for (int off = 32; off > 0; off >>= 1) v += __shfl_xor(v, off, 64);
            if (v < bestd) { bestd = v; bestk = k; }   // strict <: first-min
        }
        if (l == 0) asg_s[(w << 4) + i] = bestk;
    }
    __syncthreads();

    // ---- compact rows belonging to km (thread-0 serial: deterministic) ----
    if (tid == 0) {
        int n = 0;
        for (int r = 0; r < CHUNK; ++r)
            if (asg_s[r] == km) ls_s[n++] = r0 + r;
        cnt_s = n;
    }
    __syncthreads();
    const int cnt = cnt_s;

    const float* Wp = encW + (size_t)km * DD * HH + w * 16 + r16;
    const float* Vp = decW + (size_t)km * HH * DD + w * 64 + r16;

    // ---- per 16-row tile: enc MFMA -> e_s -> dec MFMA (R8 proven body) ----
    for (int t0 = 0; t0 < cnt; t0 += 16) {
        if (tid < 16) rs_s[tid] = (t0 + tid < cnt) ? ls_s[t0 + tid] : -1;
        __syncthreads();

        // issue enc weight batch 0 (ksteps 0..3) early
        float blA[32], blB[32];
        enc_issue(Wp, 0, g, blA);

        // stage enc A = bf16split(x[row]-c[km]) in frag layout (2 slots/thr)
        int4* Ah = frag;                 // [16 ksteps][64 lanes]
        int4* Al = frag + 1024;
        {
            const int grow = rs_s[r16];
            #pragma unroll
            for (int ss = 0; ss < 2; ++ss) {
                const int s = w + ss * 8;
                const int c0 = s * 32 + g * 8;
                float xv[8] = {0.f, 0.f, 0.f, 0.f, 0.f, 0.f, 0.f, 0.f};
                if (grow >= 0) {
                    const float4 xa = *(const float4*)(x + (size_t)grow * DD + c0);
                    const float4 xb = *(const float4*)(x + (size_t)grow * DD + c0 + 4);
                    const float4 ca = *(const float4*)(c + (size_t)km * DD + c0);
                    const float4 cb = *(const float4*)(c + (size_t)km * DD + c0 + 4);
                    xv[0] = xa.x - ca.x; xv[1] = xa.y - ca.y;
                    xv[2] = xa.z - ca.z; xv[3] = xa.w - ca.w;
                    xv[4] = xb.x - cb.x; xv[5] = xb.y - cb.y;
                    xv[6] = xb.z - cb.z; xv[7] = xb.w - cb.w;
                }
                U4 H, L;
                split2(xv[0], xv[1], H.u.x, L.u.x);
                split2(xv[2], xv[3], H.u.y, L.u.y);
                split2(xv[4], xv[5], H.u.z, L.u.z);
                split2(xv[6], xv[7], H.u.w, L.u.w);
                Ah[s * 64 + l] = H.i;    // lane-linear: conflict-free
                Al[s * 64 + l] = L.i;
            }
        }
        __syncthreads();

        // enc MFMA: wave w owns h-cols [16w,16w+16), K=512, 4x4-kstep pipe
        f4v aH = {0.f, 0.f, 0.f, 0.f}, aL = {0.f, 0.f, 0.f, 0.f};
        enc_issue(Wp, 4, g, blB);
        enc_step(Ah, Al, l, 0, blA, aH, aL);
        enc_issue(Wp, 8, g, blA);
        enc_step(Ah, Al, l, 4, blB, aH, aL);
        enc_issue(Wp, 12, g, blB);
        enc_step(Ah, Al, l, 8, blA, aH, aL);
        enc_step(Ah, Al, l, 12, blB, aH, aL);

        const float bias = encB[km * HH + w * 16 + r16];
        #pragma unroll
        for (int rr = 0; rr < 4; ++rr)
            e_s[g * 4 + rr][w * 16 + r16] = fmaxf(aH[rr] + aL[rr] + bias, 0.f);

        // issue dec weight batch 0 (kstep 0) during e-staging window
        float clA[32], clB[32];
        dec_issue(Vp, 0, g, clA);
        __syncthreads();

        // stage dec A = bf16split(e) in frag layout (256 threads, 1 slot)
        int4* Dh = frag;                 // [4 ksteps][64 lanes] (reuse bufs)
        int4* Dl = frag + 256;
        if (tid < 256) {
            const int s = tid >> 6, ll = tid & 63;
            const int c0 = s * 32 + (ll >> 4) * 8;
            const float4 ea = *(const float4*)&e_s[ll & 15][c0];
            const float4 eb = *(const float4*)&e_s[ll & 15][c0 + 4];
            U4 H, L;
            split2(ea.x, ea.y, H.u.x, L.u.x);
            split2(ea.z, ea.w, H.u.y, L.u.y);
            split2(eb.x, eb.y, H.u.z, L.u.z);
            split2(eb.z, eb.w, H.u.w, L.u.w);
            Dh[s * 64 + ll] = H.i;
            Dl[s * 64 + ll] = L.i;
        }
        __syncthreads();

        // dec MFMA: wave w owns d-cols [64w,64w+64) = 4 frags, K=128
        f4v dH[4], dL[4];
        #pragma unroll
        for (int f = 0; f < 4; ++f) {
            dH[f] = (f4v){0.f, 0.f, 0.f, 0.f};
            dL[f] = (f4v){0.f, 0.f, 0.f, 0.f};
        }
        dec_issue(Vp, 1, g, clB);
        dec_step(Dh, Dl, l, 0, clA, dH, dL);
        dec_issue(Vp, 2, g, clA);
        dec_step(Dh, Dl, l, 1, clB, dH, dL);
        dec_issue(Vp, 3, g, clB);
        dec_step(Dh, Dl, l, 2, clA, dH, dL);
        dec_step(Dh, Dl, l, 3, clB, dH, dL);

        // epilogue: + bias -> out
        #pragma unroll
        for (int f = 0; f < 4; ++f) {
            const int d = w * 64 + f * 16 + r16;
            const float db = decB[km * DD + d];
            #pragma unroll
            for (int rr = 0; rr < 4; ++rr) {
                const int grow = rs_s[g * 4 + rr];
                if (grow >= 0)
                    out[(size_t)grow * DD + d] = dH[f][rr] + dL[f][rr] + db;
            }
        }
        __syncthreads();                 // frag/e_s/rs_s safe for next tile
    }
}

extern "C" void kernel_launch(void* const* d_in, const int* in_sizes, int n_in,
                              void* d_out, int out_size, void* d_ws, size_t ws_size,
                              hipStream_t stream) {
    const float* x       = (const float*)d_in[0];
    const float* centers = (const float*)d_in[1];
    const float* enc_W   = (const float*)d_in[2];
    const float* enc_b   = (const float*)d_in[3];
    const float* dec_W   = (const float*)d_in[4];
    const float* dec_b   = (const float*)d_in[5];
    float* out = (float*)d_out;

    ae1_k<<<NCHUNK * KK, 512, 0, stream>>>(x, centers, enc_W, enc_b,
                                           dec_W, dec_b, out);
}

// Round 11
// 223.574 us; speedup vs baseline: 1.1202x; 1.1202x over previous
//
#include <hip/hip_runtime.h>

// TensorizedAutoencoder: B=2048, D=512, H=128, K=16, f32 in/out.
// R11: ONE kernel (R10's verified skeleton: grid 256 = chunk16 x cluster16,
// compact + tile-loop AE body passed at absmax 0.03125) with R10's three
// performance defects fixed:
//  1) assign via split-bf16 MFMA: G = X_chunk @ C^T (hi/lo A and B, 3 passes,
//     only Al*Bl ~2^-18 dropped); d2 = |c|^2 - 2G; 16-lane shuffle argmin
//     with first-min tie-break.  (R10's serial f32 assign was ~40us.)
//  2) ballot-based 2-wave compaction (R10's thread-0 serial LDS walk).
//  3) __launch_bounds__(512,2): 256-VGPR cap, 1 block/CU -> no spills
//     (R10 spilled ~89MB/dispatch: WRITE_SIZE 93MB).
// bid=(chunk<<4)|k -> cluster k's 16 blocks on XCD k%8 (weights L2-local).
// Fragment conventions (verified m89 + rounds 3-10):
//   A: row=l&15, k=8g+j   B: k=8g+j, col=l&15   D: col=l&15, row=4g+reg

#define BB 2048
#define DD 512
#define HH 128
#define KK 16
#define CHUNK 128
#define NCHUNK (BB / CHUNK)   // 16

typedef float f4v __attribute__((ext_vector_type(4)));
typedef short s8v __attribute__((ext_vector_type(8)));

union U4 { uint4 u; int4 i; s8v v; };

__device__ inline uint pk2(float a, float b) {   // {bf16(a), bf16(b)} packed
    uint r;
    asm("v_cvt_pk_bf16_f32 %0, %1, %2" : "=v"(r) : "v"(a), "v"(b));
    return r;
}
__device__ inline void split2(float a, float b, uint& hi, uint& lo) {
    hi = pk2(a, b);
    const float ha = __uint_as_float(hi << 16);
    const float hb = __uint_as_float(hi & 0xffff0000u);
    lo = pk2(a - ha, b - hb);                    // residual: split self-corrects
}
__device__ inline U4 packrow(const float* bl) {
    U4 r;
    r.u = make_uint4(pk2(bl[0], bl[1]), pk2(bl[2], bl[3]),
                     pk2(bl[4], bl[5]), pk2(bl[6], bl[7]));
    return r;
}

// ---- enc weight pipeline helpers (static indexing only) ----
__device__ inline void enc_issue(const float* __restrict__ Wp, int b0, int g,
                                 float bl[32]) {
    #pragma unroll
    for (int s4 = 0; s4 < 4; ++s4)
        #pragma unroll
        for (int j = 0; j < 8; ++j)
            bl[s4 * 8 + j] = Wp[(size_t)((b0 + s4) * 32 + g * 8 + j) * HH];
}
__device__ inline void enc_step(const int4* __restrict__ Ah,
                                const int4* __restrict__ Al, int l, int b0,
                                const float bl[32], f4v& aH, f4v& aL) {
    #pragma unroll
    for (int s4 = 0; s4 < 4; ++s4) {
        const U4 bf = packrow(&bl[s4 * 8]);
        U4 ah, al;
        ah.i = Ah[(b0 + s4) * 64 + l];
        al.i = Al[(b0 + s4) * 64 + l];
        aH = __builtin_amdgcn_mfma_f32_16x16x32_bf16(ah.v, bf.v, aH, 0, 0, 0);
        aL = __builtin_amdgcn_mfma_f32_16x16x32_bf16(al.v, bf.v, aL, 0, 0, 0);
    }
}
// ---- dec weight pipeline helpers (batch = kstep s, 4 f-frags) ----
__device__ inline void dec_issue(const float* __restrict__ Vp, int s, int g,
                                 float cl[32]) {
    #pragma unroll
    for (int f = 0; f < 4; ++f)
        #pragma unroll
        for (int j = 0; j < 8; ++j)
            cl[f * 8 + j] = Vp[(size_t)(s * 32 + g * 8 + j) * DD + f * 16];
}
__device__ inline void dec_step(const int4* __restrict__ Dh,
                                const int4* __restrict__ Dl, int l, int s,
                                const float cl[32], f4v dH[4], f4v dL[4]) {
    U4 ah, al;
    ah.i = Dh[s * 64 + l];
    al.i = Dl[s * 64 + l];
    #pragma unroll
    for (int f = 0; f < 4; ++f) {
        const U4 cf = packrow(&cl[f * 8]);
        dH[f] = __builtin_amdgcn_mfma_f32_16x16x32_bf16(ah.v, cf.v, dH[f], 0, 0, 0);
        dL[f] = __builtin_amdgcn_mfma_f32_16x16x32_bf16(al.v, cf.v, dL[f], 0, 0, 0);
    }
}

__global__ __launch_bounds__(512, 2) void ae1_k(const float* __restrict__ x,
                                                const float* __restrict__ c,
                                                const float* __restrict__ encW,
                                                const float* __restrict__ encB,
                                                const float* __restrict__ decW,
                                                const float* __restrict__ decB,
                                                float* __restrict__ out) {
    __shared__ int4 frag[2048];          // 32 KB: assign-A / enc-A / dec-A
    __shared__ int4 bfrag[2048];         // 32 KB: C^T hi/lo B-frags
    __shared__ float e_s[16][132];       // 8.25 KB
    __shared__ float cc_s[KK];
    __shared__ int asg_s[CHUNK];
    __shared__ int ls_s[CHUNK];
    __shared__ int rs_s[16];
    __shared__ int wtot_s[2];

    const int bid = blockIdx.x;
    const int km = bid & (KK - 1);
    const int r0 = (bid >> 4) * CHUNK;
    const int tid = threadIdx.x;
    const int w = tid >> 6, l = tid & 63;
    const int r16 = l & 15, g = l >> 4;

    // ================= phase A: assignments via split MFMA =================
    int4* Ah = frag;                     // [16 ksteps][64 lanes]
    int4* Al = frag + 1024;
    int4* Bh = bfrag;
    int4* Bl = bfrag + 1024;

    // stage B = split(C^T): lane col=r16 is cluster, k=8g+j is dim
    {
        #pragma unroll
        for (int ss = 0; ss < 2; ++ss) {
            const int s = w + ss * 8;
            const int c0 = s * 32 + g * 8;
            const float4 ca = *(const float4*)(c + (size_t)r16 * DD + c0);
            const float4 cb = *(const float4*)(c + (size_t)r16 * DD + c0 + 4);
            U4 H, L;
            split2(ca.x, ca.y, H.u.x, L.u.x);
            split2(ca.z, ca.w, H.u.y, L.u.y);
            split2(cb.x, cb.y, H.u.z, L.u.z);
            split2(cb.z, cb.w, H.u.w, L.u.w);
            Bh[s * 64 + l] = H.i;
            Bl[s * 64 + l] = L.i;
        }
    }
    // cc[k] = sum_d c[k][d]^2  (threads 0-255: k=tid>>4, 32 dims each)
    if (tid < 256) {
        const int k = tid >> 4, part = tid & 15;
        const float* cp = c + (size_t)k * DD + part * 32;
        float v = 0.f;
        #pragma unroll
        for (int q = 0; q < 8; ++q) {
            const float4 cv = *(const float4*)(cp + q * 4);
            v += cv.x * cv.x + cv.y * cv.y + cv.z * cv.z + cv.w * cv.w;
        }
        #pragma unroll
        for (int off = 1; off < 16; off <<= 1) v += __shfl_xor(v, off, 64);
        if (part == 0) cc_s[k] = v;
    }
    __syncthreads();

    // 8 row-tiles: stage A = split(x rows), MFMA 3 passes, argmin over cols
    for (int m = 0; m < 8; ++m) {
        {
            const int grow = r0 + m * 16 + r16;
            #pragma unroll
            for (int ss = 0; ss < 2; ++ss) {
                const int s = w + ss * 8;
                const int c0 = s * 32 + g * 8;
                const float4 xa = *(const float4*)(x + (size_t)grow * DD + c0);
                const float4 xb = *(const float4*)(x + (size_t)grow * DD + c0 + 4);
                U4 H, L;
                split2(xa.x, xa.y, H.u.x, L.u.x);
                split2(xa.z, xa.w, H.u.y, L.u.y);
                split2(xb.x, xb.y, H.u.z, L.u.z);
                split2(xb.z, xb.w, H.u.w, L.u.w);
                Ah[s * 64 + l] = H.i;
                Al[s * 64 + l] = L.i;
            }
        }
        __syncthreads();

        f4v accE = {0.f, 0.f, 0.f, 0.f}, accO = {0.f, 0.f, 0.f, 0.f};
        #pragma unroll
        for (int s2 = 0; s2 < 8; ++s2) {     // even/odd kstep chains for ILP
            U4 ahe, ale, bhe, ble, aho, alo, bho, blo;
            ahe.i = Ah[(2 * s2) * 64 + l];     ale.i = Al[(2 * s2) * 64 + l];
            bhe.i = Bh[(2 * s2) * 64 + l];     ble.i = Bl[(2 * s2) * 64 + l];
            aho.i = Ah[(2 * s2 + 1) * 64 + l]; alo.i = Al[(2 * s2 + 1) * 64 + l];
            bho.i = Bh[(2 * s2 + 1) * 64 + l]; blo.i = Bl[(2 * s2 + 1) * 64 + l];
            accE = __builtin_amdgcn_mfma_f32_16x16x32_bf16(ahe.v, bhe.v, accE, 0, 0, 0);
            accO = __builtin_amdgcn_mfma_f32_16x16x32_bf16(aho.v, bho.v, accO, 0, 0, 0);
            accE = __builtin_amdgcn_mfma_f32_16x16x32_bf16(ahe.v, ble.v, accE, 0, 0, 0);
            accO = __builtin_amdgcn_mfma_f32_16x16x32_bf16(aho.v, blo.v, accO, 0, 0, 0);
            accE = __builtin_amdgcn_mfma_f32_16x16x32_bf16(ale.v, bhe.v, accE, 0, 0, 0);
            accO = __builtin_amdgcn_mfma_f32_16x16x32_bf16(alo.v, bho.v, accO, 0, 0, 0);
        }
        if (w == 0) {                        // D: col=r16 (cluster), row=4g+rr
            const float ccv = cc_s[r16];
            #pragma unroll
            for (int rr = 0; rr < 4; ++rr) {
                float v = ccv - 2.0f * (accE[rr] + accO[rr]);
                int k = r16;
                #pragma unroll
                for (int off = 1; off < 16; off <<= 1) {
                    const float v2 = __shfl_xor(v, off, 64);
                    const int k2 = __shfl_xor(k, off, 64);
                    if (v2 < v || (v2 == v && k2 < k)) { v = v2; k = k2; }
                }
                if (r16 == 0) asg_s[m * 16 + g * 4 + rr] = k;
            }
        }
        __syncthreads();                     // asg written; A-buf reusable
    }

    // ============ phase B: ballot compaction of rows with asg==km ============
    {
        const bool f = (tid < CHUNK) && (asg_s[tid] == km);
        const unsigned long long bm = __ballot(f);
        const int before = __popcll(bm & ((1ull << (tid & 63)) - 1ull));
        if ((tid & 63) == 0 && (tid >> 6) < 2) wtot_s[tid >> 6] = __popcll(bm);
        __syncthreads();
        if (f) ls_s[((tid >> 6) ? wtot_s[0] : 0) + before] = r0 + tid;
        __syncthreads();
    }
    const int cnt = wtot_s[0] + wtot_s[1];

    const float* Wp = encW + (size_t)km * DD * HH + w * 16 + r16;
    const float* Vp = decW + (size_t)km * HH * DD + w * 64 + r16;

    // ===== phase C: per 16-row tile, enc MFMA -> e_s -> dec MFMA (R8 body) ====
    for (int t0 = 0; t0 < cnt; t0 += 16) {
        if (tid < 16) rs_s[tid] = (t0 + tid < cnt) ? ls_s[t0 + tid] : -1;
        __syncthreads();

        float blA[32], blB[32];
        enc_issue(Wp, 0, g, blA);

        {   // stage enc A = bf16split(x[row]-c[km]) in frag layout
            const int grow = rs_s[r16];
            #pragma unroll
            for (int ss = 0; ss < 2; ++ss) {
                const int s = w + ss * 8;
                const int c0 = s * 32 + g * 8;
                float xv[8] = {0.f, 0.f, 0.f, 0.f, 0.f, 0.f, 0.f, 0.f};
                if (grow >= 0) {
                    const float4 xa = *(const float4*)(x + (size_t)grow * DD + c0);
                    const float4 xb = *(const float4*)(x + (size_t)grow * DD + c0 + 4);
                    const float4 ca = *(const float4*)(c + (size_t)km * DD + c0);
                    const float4 cb = *(const float4*)(c + (size_t)km * DD + c0 + 4);
                    xv[0] = xa.x - ca.x; xv[1] = xa.y - ca.y;
                    xv[2] = xa.z - ca.z; xv[3] = xa.w - ca.w;
                    xv[4] = xb.x - cb.x; xv[5] = xb.y - cb.y;
                    xv[6] = xb.z - cb.z; xv[7] = xb.w - cb.w;
                }
                U4 H, L;
                split2(xv[0], xv[1], H.u.x, L.u.x);
                split2(xv[2], xv[3], H.u.y, L.u.y);
                split2(xv[4], xv[5], H.u.z, L.u.z);
                split2(xv[6], xv[7], H.u.w, L.u.w);
                Ah[s * 64 + l] = H.i;
                Al[s * 64 + l] = L.i;
            }
        }
        __syncthreads();

        // enc MFMA: wave w owns h-cols [16w,16w+16), K=512, 4x4-kstep pipe
        f4v aH = {0.f, 0.f, 0.f, 0.f}, aL = {0.f, 0.f, 0.f, 0.f};
        enc_issue(Wp, 4, g, blB);
        enc_step(Ah, Al, l, 0, blA, aH, aL);
        enc_issue(Wp, 8, g, blA);
        enc_step(Ah, Al, l, 4, blB, aH, aL);
        enc_issue(Wp, 12, g, blB);
        enc_step(Ah, Al, l, 8, blA, aH, aL);
        enc_step(Ah, Al, l, 12, blB, aH, aL);

        const float bias = encB[km * HH + w * 16 + r16];
        #pragma unroll
        for (int rr = 0; rr < 4; ++rr)
            e_s[g * 4 + rr][w * 16 + r16] = fmaxf(aH[rr] + aL[rr] + bias, 0.f);

        float clA[32], clB[32];
        dec_issue(Vp, 0, g, clA);
        __syncthreads();

        // stage dec A = bf16split(e) in frag layout (256 threads, 1 slot)
        int4* Dh = frag;
        int4* Dl = frag + 256;
        if (tid < 256) {
            const int s = tid >> 6, ll = tid & 63;
            const int c0 = s * 32 + (ll >> 4) * 8;
            const float4 ea = *(const float4*)&e_s[ll & 15][c0];
            const float4 eb = *(const float4*)&e_s[ll & 15][c0 + 4];
            U4 H, L;
            split2(ea.x, ea.y, H.u.x, L.u.x);
            split2(ea.z, ea.w, H.u.y, L.u.y);
            split2(eb.x, eb.y, H.u.z, L.u.z);
            split2(eb.z, eb.w, H.u.w, L.u.w);
            Dh[s * 64 + ll] = H.i;
            Dl[s * 64 + ll] = L.i;
        }
        __syncthreads();

        // dec MFMA: wave w owns d-cols [64w,64w+64) = 4 frags, K=128
        f4v dH[4], dL[4];
        #pragma unroll
        for (int f = 0; f < 4; ++f) {
            dH[f] = (f4v){0.f, 0.f, 0.f, 0.f};
            dL[f] = (f4v){0.f, 0.f, 0.f, 0.f};
        }
        dec_issue(Vp, 1, g, clB);
        dec_step(Dh, Dl, l, 0, clA, dH, dL);
        dec_issue(Vp, 2, g, clA);
        dec_step(Dh, Dl, l, 1, clB, dH, dL);
        dec_issue(Vp, 3, g, clB);
        dec_step(Dh, Dl, l, 2, clA, dH, dL);
        dec_step(Dh, Dl, l, 3, clB, dH, dL);

        // epilogue: + bias -> out
        #pragma unroll
        for (int f = 0; f < 4; ++f) {
            const int d = w * 64 + f * 16 + r16;
            const float db = decB[km * DD + d];
            #pragma unroll
            for (int rr = 0; rr < 4; ++rr) {
                const int grow = rs_s[g * 4 + rr];
                if (grow >= 0)
                    out[(size_t)grow * DD + d] = dH[f][rr] + dL[f][rr] + db;
            }
        }
        __syncthreads();                 // frag/e_s/rs_s safe for next tile
    }
}

extern "C" void kernel_launch(void* const* d_in, const int* in_sizes, int n_in,
                              void* d_out, int out_size, void* d_ws, size_t ws_size,
                              hipStream_t stream) {
    const float* x       = (const float*)d_in[0];
    const float* centers = (const float*)d_in[1];
    const float* enc_W   = (const float*)d_in[2];
    const float* enc_b   = (const float*)d_in[3];
    const float* dec_W   = (const float*)d_in[4];
    const float* dec_b   = (const float*)d_in[5];
    float* out = (float*)d_out;

    ae1_k<<<NCHUNK * KK, 512, 0, stream>>>(x, centers, enc_W, enc_b,
                                           dec_W, dec_b, out);
}

// Round 12
// 218.552 us; speedup vs baseline: 1.1459x; 1.0230x over previous
//
#include <hip/hip_runtime.h>

// TensorizedAutoencoder: B=2048, D=512, H=128, K=16, f32 in/out.
// R12: R11's verified single-kernel structure (passed, absmax 0.03125) with
// the spill killed (R11: VGPR=128 + 93MB scratch WRITE_SIZE = the whole
// 223us). Two spill-targeted changes, arithmetic bit-identical:
//  1) __launch_bounds__(512,1): allow up to the 2-waves/SIMD VGPR cap (256).
//  2) 16-float pipeline batches (2 ksteps enc / 2 frags dec), hand-unrolled
//     literal indices: peak weight-staging live set 128 -> 32 floats.
// Grid 256 = (chunk 16 x cluster 16); block (c,k): assign via split-bf16
// MFMA (G = X @ C^T, 3 passes) -> ballot compact -> enc/dec MFMA tiles.
// bid=(chunk<<4)|k -> cluster k's 16 blocks on XCD k%8 (weights L2-local).
// Fragment conventions (verified m89 + rounds 3-11):
//   A: row=l&15, k=8g+j   B: k=8g+j, col=l&15   D: col=l&15, row=4g+reg

#define BB 2048
#define DD 512
#define HH 128
#define KK 16
#define CHUNK 128
#define NCHUNK (BB / CHUNK)   // 16

typedef float f4v __attribute__((ext_vector_type(4)));
typedef short s8v __attribute__((ext_vector_type(8)));

union U4 { uint4 u; int4 i; s8v v; };

__device__ inline uint pk2(float a, float b) {   // {bf16(a), bf16(b)} packed
    uint r;
    asm("v_cvt_pk_bf16_f32 %0, %1, %2" : "=v"(r) : "v"(a), "v"(b));
    return r;
}
__device__ inline void split2(float a, float b, uint& hi, uint& lo) {
    hi = pk2(a, b);
    const float ha = __uint_as_float(hi << 16);
    const float hb = __uint_as_float(hi & 0xffff0000u);
    lo = pk2(a - ha, b - hb);                    // residual: split self-corrects
}
__device__ inline U4 packrow(const float* bl) {
    U4 r;
    r.u = make_uint4(pk2(bl[0], bl[1]), pk2(bl[2], bl[3]),
                     pk2(bl[4], bl[5]), pk2(bl[6], bl[7]));
    return r;
}

// ---- enc pipeline: 2-kstep (16-float) batches, literal b0 at call sites ----
__device__ inline void enc_issue2(const float* __restrict__ Wp, int b0, int g,
                                  float bl[16]) {
    #pragma unroll
    for (int s = 0; s < 2; ++s)
        #pragma unroll
        for (int j = 0; j < 8; ++j)
            bl[s * 8 + j] = Wp[(size_t)((b0 + s) * 32 + g * 8 + j) * HH];
}
__device__ inline void enc_step2(const int4* __restrict__ Ah,
                                 const int4* __restrict__ Al, int l, int b0,
                                 const float bl[16], f4v& aH, f4v& aL) {
    #pragma unroll
    for (int s = 0; s < 2; ++s) {
        const U4 bf = packrow(&bl[s * 8]);
        U4 ah, al;
        ah.i = Ah[(b0 + s) * 64 + l];
        al.i = Al[(b0 + s) * 64 + l];
        aH = __builtin_amdgcn_mfma_f32_16x16x32_bf16(ah.v, bf.v, aH, 0, 0, 0);
        aL = __builtin_amdgcn_mfma_f32_16x16x32_bf16(al.v, bf.v, aL, 0, 0, 0);
    }
}
// ---- dec pipeline: 2-frag (16-float) batches, p = (kstep<<1)|fpair ----
__device__ inline void dec_issue2(const float* __restrict__ Vp, int p, int g,
                                  float cl[16]) {
    const int s = p >> 1, f0 = (p & 1) * 2;
    #pragma unroll
    for (int fi = 0; fi < 2; ++fi)
        #pragma unroll
        for (int j = 0; j < 8; ++j)
            cl[fi * 8 + j] = Vp[(size_t)(s * 32 + g * 8 + j) * DD + (f0 + fi) * 16];
}
__device__ inline void dec_step2(const int4* __restrict__ Dh,
                                 const int4* __restrict__ Dl, int l, int p,
                                 const float cl[16], f4v dH[4], f4v dL[4]) {
    const int s = p >> 1, f0 = (p & 1) * 2;
    U4 ah, al;
    ah.i = Dh[s * 64 + l];
    al.i = Dl[s * 64 + l];
    #pragma unroll
    for (int fi = 0; fi < 2; ++fi) {
        const U4 cf = packrow(&cl[fi * 8]);
        dH[f0 + fi] = __builtin_amdgcn_mfma_f32_16x16x32_bf16(ah.v, cf.v, dH[f0 + fi], 0, 0, 0);
        dL[f0 + fi] = __builtin_amdgcn_mfma_f32_16x16x32_bf16(al.v, cf.v, dL[f0 + fi], 0, 0, 0);
    }
}

__global__ __launch_bounds__(512, 1) void ae1_k(const float* __restrict__ x,
                                                const float* __restrict__ c,
                                                const float* __restrict__ encW,
                                                const float* __restrict__ encB,
                                                const float* __restrict__ decW,
                                                const float* __restrict__ decB,
                                                float* __restrict__ out) {
    __shared__ int4 frag[2048];          // 32 KB: assign-A / enc-A / dec-A
    __shared__ int4 bfrag[2048];         // 32 KB: C^T hi/lo B-frags
    __shared__ float e_s[16][132];       // 8.25 KB
    __shared__ float cc_s[KK];
    __shared__ int asg_s[CHUNK];
    __shared__ int ls_s[CHUNK];
    __shared__ int rs_s[16];
    __shared__ int wtot_s[2];

    const int bid = blockIdx.x;
    const int km = bid & (KK - 1);
    const int r0 = (bid >> 4) * CHUNK;
    const int tid = threadIdx.x;
    const int w = tid >> 6, l = tid & 63;
    const int r16 = l & 15, g = l >> 4;

    // ================= phase A: assignments via split MFMA =================
    int4* Ah = frag;                     // [16 ksteps][64 lanes]
    int4* Al = frag + 1024;
    int4* Bh = bfrag;
    int4* Bl = bfrag + 1024;

    // stage B = split(C^T): lane col=r16 is cluster, k=8g+j is dim
    {
        #pragma unroll
        for (int ss = 0; ss < 2; ++ss) {
            const int s = w + ss * 8;
            const int c0 = s * 32 + g * 8;
            const float4 ca = *(const float4*)(c + (size_t)r16 * DD + c0);
            const float4 cb = *(const float4*)(c + (size_t)r16 * DD + c0 + 4);
            U4 H, L;
            split2(ca.x, ca.y, H.u.x, L.u.x);
            split2(ca.z, ca.w, H.u.y, L.u.y);
            split2(cb.x, cb.y, H.u.z, L.u.z);
            split2(cb.z, cb.w, H.u.w, L.u.w);
            Bh[s * 64 + l] = H.i;
            Bl[s * 64 + l] = L.i;
        }
    }
    // cc[k] = sum_d c[k][d]^2  (threads 0-255: k=tid>>4, 32 dims each)
    if (tid < 256) {
        const int k = tid >> 4, part = tid & 15;
        const float* cp = c + (size_t)k * DD + part * 32;
        float v = 0.f;
        #pragma unroll
        for (int q = 0; q < 8; ++q) {
            const float4 cv = *(const float4*)(cp + q * 4);
            v += cv.x * cv.x + cv.y * cv.y + cv.z * cv.z + cv.w * cv.w;
        }
        #pragma unroll
        for (int off = 1; off < 16; off <<= 1) v += __shfl_xor(v, off, 64);
        if (part == 0) cc_s[k] = v;
    }
    __syncthreads();

    // 8 row-tiles: stage A = split(x rows), MFMA 3 passes, argmin over cols
    for (int m = 0; m < 8; ++m) {
        {
            const int grow = r0 + m * 16 + r16;
            #pragma unroll
            for (int ss = 0; ss < 2; ++ss) {
                const int s = w + ss * 8;
                const int c0 = s * 32 + g * 8;
                const float4 xa = *(const float4*)(x + (size_t)grow * DD + c0);
                const float4 xb = *(const float4*)(x + (size_t)grow * DD + c0 + 4);
                U4 H, L;
                split2(xa.x, xa.y, H.u.x, L.u.x);
                split2(xa.z, xa.w, H.u.y, L.u.y);
                split2(xb.x, xb.y, H.u.z, L.u.z);
                split2(xb.z, xb.w, H.u.w, L.u.w);
                Ah[s * 64 + l] = H.i;
                Al[s * 64 + l] = L.i;
            }
        }
        __syncthreads();

        f4v accE = {0.f, 0.f, 0.f, 0.f}, accO = {0.f, 0.f, 0.f, 0.f};
        #pragma unroll
        for (int s2 = 0; s2 < 8; ++s2) {     // even/odd kstep chains for ILP
            U4 ahe, ale, bhe, ble, aho, alo, bho, blo;
            ahe.i = Ah[(2 * s2) * 64 + l];     ale.i = Al[(2 * s2) * 64 + l];
            bhe.i = Bh[(2 * s2) * 64 + l];     ble.i = Bl[(2 * s2) * 64 + l];
            aho.i = Ah[(2 * s2 + 1) * 64 + l]; alo.i = Al[(2 * s2 + 1) * 64 + l];
            bho.i = Bh[(2 * s2 + 1) * 64 + l]; blo.i = Bl[(2 * s2 + 1) * 64 + l];
            accE = __builtin_amdgcn_mfma_f32_16x16x32_bf16(ahe.v, bhe.v, accE, 0, 0, 0);
            accO = __builtin_amdgcn_mfma_f32_16x16x32_bf16(aho.v, bho.v, accO, 0, 0, 0);
            accE = __builtin_amdgcn_mfma_f32_16x16x32_bf16(ahe.v, ble.v, accE, 0, 0, 0);
            accO = __builtin_amdgcn_mfma_f32_16x16x32_bf16(aho.v, blo.v, accO, 0, 0, 0);
            accE = __builtin_amdgcn_mfma_f32_16x16x32_bf16(ale.v, bhe.v, accE, 0, 0, 0);
            accO = __builtin_amdgcn_mfma_f32_16x16x32_bf16(alo.v, bho.v, accO, 0, 0, 0);
        }
        if (w == 0) {                        // D: col=r16 (cluster), row=4g+rr
            const float ccv = cc_s[r16];
            #pragma unroll
            for (int rr = 0; rr < 4; ++rr) {
                float v = ccv - 2.0f * (accE[rr] + accO[rr]);
                int k = r16;
                #pragma unroll
                for (int off = 1; off < 16; off <<= 1) {
                    const float v2 = __shfl_xor(v, off, 64);
                    const int k2 = __shfl_xor(k, off, 64);
                    if (v2 < v || (v2 == v && k2 < k)) { v = v2; k = k2; }
                }
                if (r16 == 0) asg_s[m * 16 + g * 4 + rr] = k;
            }
        }
        __syncthreads();                     // asg written; A-buf reusable
    }

    // ============ phase B: ballot compaction of rows with asg==km ============
    {
        const bool f = (tid < CHUNK) && (asg_s[tid] == km);
        const unsigned long long bm = __ballot(f);
        const int before = __popcll(bm & ((1ull << (tid & 63)) - 1ull));
        if ((tid & 63) == 0 && (tid >> 6) < 2) wtot_s[tid >> 6] = __popcll(bm);
        __syncthreads();
        if (f) ls_s[((tid >> 6) ? wtot_s[0] : 0) + before] = r0 + tid;
        __syncthreads();
    }
    const int cnt = wtot_s[0] + wtot_s[1];

    const float* Wp = encW + (size_t)km * DD * HH + w * 16 + r16;
    const float* Vp = decW + (size_t)km * HH * DD + w * 64 + r16;

    // ===== phase C: per 16-row tile, enc MFMA -> e_s -> dec MFMA =====
    for (int t0 = 0; t0 < cnt; t0 += 16) {
        if (tid < 16) rs_s[tid] = (t0 + tid < cnt) ? ls_s[t0 + tid] : -1;
        __syncthreads();

        float blA[16], blB[16];
        enc_issue2(Wp, 0, g, blA);

        {   // stage enc A = bf16split(x[row]-c[km]) in frag layout
            const int grow = rs_s[r16];
            #pragma unroll
            for (int ss = 0; ss < 2; ++ss) {
                const int s = w + ss * 8;
                const int c0 = s * 32 + g * 8;
                float xv[8] = {0.f, 0.f, 0.f, 0.f, 0.f, 0.f, 0.f, 0.f};
                if (grow >= 0) {
                    const float4 xa = *(const float4*)(x + (size_t)grow * DD + c0);
                    const float4 xb = *(const float4*)(x + (size_t)grow * DD + c0 + 4);
                    const float4 ca = *(const float4*)(c + (size_t)km * DD + c0);
                    const float4 cb = *(const float4*)(c + (size_t)km * DD + c0 + 4);
                    xv[0] = xa.x - ca.x; xv[1] = xa.y - ca.y;
                    xv[2] = xa.z - ca.z; xv[3] = xa.w - ca.w;
                    xv[4] = xb.x - cb.x; xv[5] = xb.y - cb.y;
                    xv[6] = xb.z - cb.z; xv[7] = xb.w - cb.w;
                }
                U4 H, L;
                split2(xv[0], xv[1], H.u.x, L.u.x);
                split2(xv[2], xv[3], H.u.y, L.u.y);
                split2(xv[4], xv[5], H.u.z, L.u.z);
                split2(xv[6], xv[7], H.u.w, L.u.w);
                Ah[s * 64 + l] = H.i;
                Al[s * 64 + l] = L.i;
            }
        }
        __syncthreads();

        // enc MFMA: wave w owns h-cols [16w,16w+16), K=512, 8x2-kstep pipe
        f4v aH = {0.f, 0.f, 0.f, 0.f}, aL = {0.f, 0.f, 0.f, 0.f};
        enc_issue2(Wp, 2, g, blB);
        enc_step2(Ah, Al, l, 0, blA, aH, aL);
        enc_issue2(Wp, 4, g, blA);
        enc_step2(Ah, Al, l, 2, blB, aH, aL);
        enc_issue2(Wp, 6, g, blB);
        enc_step2(Ah, Al, l, 4, blA, aH, aL);
        enc_issue2(Wp, 8, g, blA);
        enc_step2(Ah, Al, l, 6, blB, aH, aL);
        enc_issue2(Wp, 10, g, blB);
        enc_step2(Ah, Al, l, 8, blA, aH, aL);
        enc_issue2(Wp, 12, g, blA);
        enc_step2(Ah, Al, l, 10, blB, aH, aL);
        enc_issue2(Wp, 14, g, blB);
        enc_step2(Ah, Al, l, 12, blA, aH, aL);
        enc_step2(Ah, Al, l, 14, blB, aH, aL);

        const float bias = encB[km * HH + w * 16 + r16];
        #pragma unroll
        for (int rr = 0; rr < 4; ++rr)
            e_s[g * 4 + rr][w * 16 + r16] = fmaxf(aH[rr] + aL[rr] + bias, 0.f);

        float clA[16], clB[16];
        dec_issue2(Vp, 0, g, clA);           // s0 f0-1, fills e-staging window
        __syncthreads();

        // stage dec A = bf16split(e) in frag layout (256 threads, 1 slot)
        int4* Dh = frag;
        int4* Dl = frag + 256;
        if (tid < 256) {
            const int s = tid >> 6, ll = tid & 63;
            const int c0 = s * 32 + (ll >> 4) * 8;
            const float4 ea = *(const float4*)&e_s[ll & 15][c0];
            const float4 eb = *(const float4*)&e_s[ll & 15][c0 + 4];
            U4 H, L;
            split2(ea.x, ea.y, H.u.x, L.u.x);
            split2(ea.z, ea.w, H.u.y, L.u.y);
            split2(eb.x, eb.y, H.u.z, L.u.z);
            split2(eb.z, eb.w, H.u.w, L.u.w);
            Dh[s * 64 + ll] = H.i;
            Dl[s * 64 + ll] = L.i;
        }
        __syncthreads();

        // dec MFMA: wave w owns d-cols [64w,64w+64) = 4 frags, K=128
        f4v dH[4], dL[4];
        #pragma unroll
        for (int f = 0; f < 4; ++f) {
            dH[f] = (f4v){0.f, 0.f, 0.f, 0.f};
            dL[f] = (f4v){0.f, 0.f, 0.f, 0.f};
        }
        dec_issue2(Vp, 1, g, clB);
        dec_step2(Dh, Dl, l, 0, clA, dH, dL);
        dec_issue2(Vp, 2, g, clA);
        dec_step2(Dh, Dl, l, 1, clB, dH, dL);
        dec_issue2(Vp, 3, g, clB);
        dec_step2(Dh, Dl, l, 2, clA, dH, dL);
        dec_issue2(Vp, 4, g, clA);
        dec_step2(Dh, Dl, l, 3, clB, dH, dL);
        dec_issue2(Vp, 5, g, clB);
        dec_step2(Dh, Dl, l, 4, clA, dH, dL);
        dec_issue2(Vp, 6, g, clA);
        dec_step2(Dh, Dl, l, 5, clB, dH, dL);
        dec_issue2(Vp, 7, g, clB);
        dec_step2(Dh, Dl, l, 6, clA, dH, dL);
        dec_step2(Dh, Dl, l, 7, clB, dH, dL);

        // epilogue: + bias -> out
        #pragma unroll
        for (int f = 0; f < 4; ++f) {
            const int d = w * 64 + f * 16 + r16;
            const float db = decB[km * DD + d];
            #pragma unroll
            for (int rr = 0; rr < 4; ++rr) {
                const int grow = rs_s[g * 4 + rr];
                if (grow >= 0)
                    out[(size_t)grow * DD + d] = dH[f][rr] + dL[f][rr] + db;
            }
        }
        __syncthreads();                 // frag/e_s/rs_s safe for next tile
    }
}

extern "C" void kernel_launch(void* const* d_in, const int* in_sizes, int n_in,
                              void* d_out, int out_size, void* d_ws, size_t ws_size,
                              hipStream_t stream) {
    const float* x       = (const float*)d_in[0];
    const float* centers = (const float*)d_in[1];
    const float* enc_W   = (const float*)d_in[2];
    const float* enc_b   = (const float*)d_in[3];
    const float* dec_W   = (const float*)d_in[4];
    const float* dec_b   = (const float*)d_in[5];
    float* out = (float*)d_out;

    ae1_k<<<NCHUNK * KK, 512, 0, stream>>>(x, centers, enc_W, enc_b,
                                           dec_W, dec_b, out);
}

// Round 13
// 116.436 us; speedup vs baseline: 2.1509x; 1.8770x over previous
//
#include <hip/hip_runtime.h>

// TensorizedAutoencoder: B=2048, D=512, H=128, K=16, f32 in/out.
// R13: single kernel, scratch-pressure removed at the source.
//  - Phase A: per-wave MFMA assignment. Wave w assigns chunk rows w*16..+15:
//    A-frags (hi/lo split x) built in registers, B = split(C^T) staged once
//    in LDS, 3-pass chain (hh, hl, lh; ll ~2^-18 dropped), d2 = |c|^2 - 2G,
//    16-lane shuffle argmin, first-min tie-break. No LDS A-staging, no
//    redundant MFMA issue (R12 issued 8x), no per-m barriers.
//  - Phase B: ballot compaction (verified R11/R12).
//  - Phase C: per-16-row-tile loop with R7's SIMPLE enc/dec inner loops
//    (8 scalar loads -> pack -> MFMA; measured VGPR 68 / zero scratch in R7).
//    R8-style register pipelining is what blew up pressure inside the loop
//    (R10-R12: 86-93MB scratch = the entire runtime) -- removed.
// Grid 256 = (chunk 16 x cluster 16); bid&15=cluster -> same-cluster blocks
// share an XCD (weights L2-local). Fragment conventions (m89, rounds 3-12):
//   A: row=l&15, k=8g+j   B: k=8g+j, col=l&15   D: col=l&15, row=4g+reg

#define BB 2048
#define DD 512
#define HH 128
#define KK 16
#define CHUNK 128
#define NCHUNK (BB / CHUNK)   // 16

typedef float f4v __attribute__((ext_vector_type(4)));
typedef short s8v __attribute__((ext_vector_type(8)));

union U4 { uint4 u; int4 i; s8v v; };

__device__ __attribute__((always_inline)) inline uint pk2(float a, float b) {
    uint r;
    asm("v_cvt_pk_bf16_f32 %0, %1, %2" : "=v"(r) : "v"(a), "v"(b));
    return r;
}
__device__ __attribute__((always_inline)) inline void split2(float a, float b,
                                                             uint& hi, uint& lo) {
    hi = pk2(a, b);
    const float ha = __uint_as_float(hi << 16);
    const float hb = __uint_as_float(hi & 0xffff0000u);
    lo = pk2(a - ha, b - hb);                    // residual: split self-corrects
}
__device__ __attribute__((always_inline)) inline U4 packrow(const float* bl) {
    U4 r;
    r.u = make_uint4(pk2(bl[0], bl[1]), pk2(bl[2], bl[3]),
                     pk2(bl[4], bl[5]), pk2(bl[6], bl[7]));
    return r;
}

__global__ __launch_bounds__(512, 2) void ae1_k(const float* __restrict__ x,
                                                const float* __restrict__ c,
                                                const float* __restrict__ encW,
                                                const float* __restrict__ encB,
                                                const float* __restrict__ decW,
                                                const float* __restrict__ decB,
                                                float* __restrict__ out) {
    __shared__ int4 frag[2048];          // 32 KB: phase-A B-frags / phase-C A-frags
    __shared__ float e_s[16][132];       // 8.25 KB
    __shared__ float cc_s[KK];
    __shared__ int asg_s[CHUNK];
    __shared__ int ls_s[CHUNK];
    __shared__ int rs_s[16];
    __shared__ int wtot_s[2];

    const int bid = blockIdx.x;
    const int km = bid & (KK - 1);
    const int r0 = (bid >> 4) * CHUNK;
    const int tid = threadIdx.x;
    const int w = tid >> 6, l = tid & 63;
    const int r16 = l & 15, g = l >> 4;

    // ======== phase A: per-wave MFMA assignment of the 128-row chunk ========
    int4* Bh = frag;                     // [16 ksteps][64 lanes]
    int4* Bl = frag + 1024;

    {   // stage B = split(C^T): col=r16 is cluster, k=8g+j is dim s*32+g*8+j
        #pragma unroll
        for (int ss = 0; ss < 2; ++ss) {
            const int s = w + ss * 8;
            const int c0 = s * 32 + g * 8;
            const float4 ca = *(const float4*)(c + (size_t)r16 * DD + c0);
            const float4 cb = *(const float4*)(c + (size_t)r16 * DD + c0 + 4);
            U4 H, L;
            split2(ca.x, ca.y, H.u.x, L.u.x);
            split2(ca.z, ca.w, H.u.y, L.u.y);
            split2(cb.x, cb.y, H.u.z, L.u.z);
            split2(cb.z, cb.w, H.u.w, L.u.w);
            Bh[s * 64 + l] = H.i;
            Bl[s * 64 + l] = L.i;
        }
    }
    // cc[k] = sum_d c[k][d]^2  (threads 0-255: k=tid>>4, 32 dims each)
    if (tid < 256) {
        const int k = tid >> 4, part = tid & 15;
        const float* cp = c + (size_t)k * DD + part * 32;
        float v = 0.f;
        #pragma unroll
        for (int q = 0; q < 8; ++q) {
            const float4 cv = *(const float4*)(cp + q * 4);
            v += cv.x * cv.x + cv.y * cv.y + cv.z * cv.z + cv.w * cv.w;
        }
        #pragma unroll
        for (int off = 1; off < 16; off <<= 1) v += __shfl_xor(v, off, 64);
        if (part == 0) cc_s[k] = v;
    }
    __syncthreads();

    {   // wave w: rows r0+w*16+r16; A-frag in registers per kstep; 3-pass MFMA
        const int grow = r0 + (w << 4) + r16;
        f4v acc = {0.f, 0.f, 0.f, 0.f};
        #pragma unroll 4
        for (int s = 0; s < 16; ++s) {
            const int c0 = s * 32 + g * 8;
            const float4 xa = *(const float4*)(x + (size_t)grow * DD + c0);
            const float4 xb = *(const float4*)(x + (size_t)grow * DD + c0 + 4);
            U4 ah, al;
            split2(xa.x, xa.y, ah.u.x, al.u.x);
            split2(xa.z, xa.w, ah.u.y, al.u.y);
            split2(xb.x, xb.y, ah.u.z, al.u.z);
            split2(xb.z, xb.w, ah.u.w, al.u.w);
            U4 bh, bl2;
            bh.i  = Bh[s * 64 + l];
            bl2.i = Bl[s * 64 + l];
            acc = __builtin_amdgcn_mfma_f32_16x16x32_bf16(ah.v, bh.v, acc, 0, 0, 0);
            acc = __builtin_amdgcn_mfma_f32_16x16x32_bf16(ah.v, bl2.v, acc, 0, 0, 0);
            acc = __builtin_amdgcn_mfma_f32_16x16x32_bf16(al.v, bh.v, acc, 0, 0, 0);
        }
        // D: col=r16 (cluster), row=4g+rr (row within wave's 16-row tile)
        const float ccv = cc_s[r16];
        #pragma unroll
        for (int rr = 0; rr < 4; ++rr) {
            float v = ccv - 2.0f * acc[rr];
            int k = r16;
            #pragma unroll
            for (int off = 1; off < 16; off <<= 1) {   // within 16-lane group
                const float v2 = __shfl_xor(v, off, 64);
                const int k2 = __shfl_xor(k, off, 64);
                if (v2 < v || (v2 == v && k2 < k)) { v = v2; k = k2; }
            }
            if (r16 == 0) asg_s[(w << 4) + g * 4 + rr] = k;
        }
    }
    __syncthreads();

    // ============ phase B: ballot compaction of rows with asg==km ============
    {
        const bool f = (tid < CHUNK) && (asg_s[tid] == km);
        const unsigned long long bm = __ballot(f);
        const int before = __popcll(bm & ((1ull << (tid & 63)) - 1ull));
        if ((tid & 63) == 0 && (tid >> 6) < 2) wtot_s[tid >> 6] = __popcll(bm);
        __syncthreads();
        if (f) ls_s[((tid >> 6) ? wtot_s[0] : 0) + before] = r0 + tid;
        __syncthreads();
    }
    const int cnt = wtot_s[0] + wtot_s[1];

    // ===== phase C: per 16-row tile, R7-style enc MFMA -> e_s -> dec MFMA ====
    int4* Ah = frag;                     // reuse (phase-A reads all done)
    int4* Al = frag + 1024;

    for (int t0 = 0; t0 < cnt; t0 += 16) {
        if (tid < 16) rs_s[tid] = (t0 + tid < cnt) ? ls_s[t0 + tid] : -1;
        __syncthreads();

        {   // stage enc A = bf16split(x[row]-c[km]) in frag layout (2 slots/thr)
            const int grow = rs_s[r16];
            #pragma unroll
            for (int ss = 0; ss < 2; ++ss) {
                const int s = w + ss * 8;
                const int c0 = s * 32 + g * 8;
                float xv[8] = {0.f, 0.f, 0.f, 0.f, 0.f, 0.f, 0.f, 0.f};
                if (grow >= 0) {
                    const float4 xa = *(const float4*)(x + (size_t)grow * DD + c0);
                    const float4 xb = *(const float4*)(x + (size_t)grow * DD + c0 + 4);
                    const float4 ca = *(const float4*)(c + (size_t)km * DD + c0);
                    const float4 cb = *(const float4*)(c + (size_t)km * DD + c0 + 4);
                    xv[0] = xa.x - ca.x; xv[1] = xa.y - ca.y;
                    xv[2] = xa.z - ca.z; xv[3] = xa.w - ca.w;
                    xv[4] = xb.x - cb.x; xv[5] = xb.y - cb.y;
                    xv[6] = xb.z - cb.z; xv[7] = xb.w - cb.w;
                }
                U4 H, L;
                split2(xv[0], xv[1], H.u.x, L.u.x);
                split2(xv[2], xv[3], H.u.y, L.u.y);
                split2(xv[4], xv[5], H.u.z, L.u.z);
                split2(xv[6], xv[7], H.u.w, L.u.w);
                Ah[s * 64 + l] = H.i;    // lane-linear: conflict-free
                Al[s * 64 + l] = L.i;
            }
        }
        __syncthreads();

        // enc MFMA (R7 body): wave w owns h-cols [16w,16w+16), K=512
        {
            f4v aH = {0.f, 0.f, 0.f, 0.f}, aL = {0.f, 0.f, 0.f, 0.f};
            const float* Wp = encW + (size_t)km * DD * HH + w * 16 + r16;
            #pragma unroll 4
            for (int s = 0; s < 16; ++s) {
                U4 ah, al;
                ah.i = Ah[s * 64 + l];
                al.i = Al[s * 64 + l];
                const float* wp = Wp + (size_t)(s * 32 + g * 8) * HH;
                float bl[8];
                #pragma unroll
                for (int j = 0; j < 8; ++j) bl[j] = wp[(size_t)j * HH];
                const U4 bf = packrow(bl);
                aH = __builtin_amdgcn_mfma_f32_16x16x32_bf16(ah.v, bf.v, aH, 0, 0, 0);
                aL = __builtin_amdgcn_mfma_f32_16x16x32_bf16(al.v, bf.v, aL, 0, 0, 0);
            }
            const float bias = encB[km * HH + w * 16 + r16];
            #pragma unroll
            for (int rr = 0; rr < 4; ++rr)
                e_s[g * 4 + rr][w * 16 + r16] = fmaxf(aH[rr] + aL[rr] + bias, 0.f);
        }
        __syncthreads();

        // stage dec A = bf16split(e) in frag layout (256 threads, 1 slot)
        int4* Dh = frag;
        int4* Dl = frag + 256;
        if (tid < 256) {
            const int s = tid >> 6, ll = tid & 63;
            const int c0 = s * 32 + (ll >> 4) * 8;
            const float4 ea = *(const float4*)&e_s[ll & 15][c0];
            const float4 eb = *(const float4*)&e_s[ll & 15][c0 + 4];
            U4 H, L;
            split2(ea.x, ea.y, H.u.x, L.u.x);
            split2(ea.z, ea.w, H.u.y, L.u.y);
            split2(eb.x, eb.y, H.u.z, L.u.z);
            split2(eb.z, eb.w, H.u.w, L.u.w);
            Dh[s * 64 + ll] = H.i;
            Dl[s * 64 + ll] = L.i;
        }
        __syncthreads();

        // dec MFMA (R7 body): wave w owns d-cols [64w,64w+64) = 4 frags, K=128
        {
            f4v dH[4], dL[4];
            #pragma unroll
            for (int f = 0; f < 4; ++f) {
                dH[f] = (f4v){0.f, 0.f, 0.f, 0.f};
                dL[f] = (f4v){0.f, 0.f, 0.f, 0.f};
            }
            const float* Vp = decW + (size_t)km * HH * DD + w * 64 + r16;
            #pragma unroll
            for (int s = 0; s < 4; ++s) {
                U4 ah, al;
                ah.i = Dh[s * 64 + l];
                al.i = Dl[s * 64 + l];
                const float* vp = Vp + (size_t)(s * 32 + g * 8) * DD;
                #pragma unroll
                for (int f = 0; f < 4; ++f) {
                    float bl[8];
                    #pragma unroll
                    for (int j = 0; j < 8; ++j) bl[j] = vp[(size_t)j * DD + f * 16];
                    const U4 cf = packrow(bl);
                    dH[f] = __builtin_amdgcn_mfma_f32_16x16x32_bf16(ah.v, cf.v, dH[f], 0, 0, 0);
                    dL[f] = __builtin_amdgcn_mfma_f32_16x16x32_bf16(al.v, cf.v, dL[f], 0, 0, 0);
                }
            }
            // epilogue: + bias -> out
            #pragma unroll
            for (int f = 0; f < 4; ++f) {
                const int d = w * 64 + f * 16 + r16;
                const float db = decB[km * DD + d];
                #pragma unroll
                for (int rr = 0; rr < 4; ++rr) {
                    const int grow = rs_s[g * 4 + rr];
                    if (grow >= 0)
                        out[(size_t)grow * DD + d] = dH[f][rr] + dL[f][rr] + db;
                }
            }
        }
        __syncthreads();                 // frag/e_s/rs_s safe for next tile
    }
}

extern "C" void kernel_launch(void* const* d_in, const int* in_sizes, int n_in,
                              void* d_out, int out_size, void* d_ws, size_t ws_size,
                              hipStream_t stream) {
    const float* x       = (const float*)d_in[0];
    const float* centers = (const float*)d_in[1];
    const float* enc_W   = (const float*)d_in[2];
    const float* enc_b   = (const float*)d_in[3];
    const float* dec_W   = (const float*)d_in[4];
    const float* dec_b   = (const float*)d_in[5];
    float* out = (float*)d_out;

    ae1_k<<<NCHUNK * KK, 512, 0, stream>>>(x, centers, enc_W, enc_b,
                                           dec_W, dec_b, out);
}

// Round 14
// 33.433 us; speedup vs baseline: 7.4911x; 3.4827x over previous
//
#include <hip/hip_runtime.h>

// TensorizedAutoencoder: B=2048, D=512, H=128, K=16, f32 in/out.
// R14: revert to the 2-kernel R8 structure (27.8us known-good; the fused
// single kernel spilled scratch in all 4 attempts R10-R13). One improvement
// kept from the failed branch: assign via split-bf16 MFMA (verified correct
// in R11/R12/R13, absmax unchanged 3x) as a standalone kernel -- 32 blocks
// x 4 waves, wave assigns 16 rows, ~3x faster than the serial-k original.
// ae_k is byte-identical to R8's (hist2 transposed scan + batched weight
// prefetch enc/dec MFMA). Fragment conventions (m89, rounds 3-13):
//   A: row=l&15, k=8g+j   B: k=8g+j, col=l&15   D: col=l&15, row=4g+reg

#define BB 2048
#define DD 512
#define HH 128
#define KK 16
#define MAXTILES 143   // max sum of ceil(cnt_k/16) = 128 + 15

typedef float f4v __attribute__((ext_vector_type(4)));
typedef short s8v __attribute__((ext_vector_type(8)));

union U4 { uint4 u; int4 i; s8v v; };

__device__ inline uint pk2(float a, float b) {   // {bf16(a), bf16(b)} packed
    uint r;
    asm("v_cvt_pk_bf16_f32 %0, %1, %2" : "=v"(r) : "v"(a), "v"(b));
    return r;
}
__device__ inline void split2(float a, float b, uint& hi, uint& lo) {
    hi = pk2(a, b);
    const float ha = __uint_as_float(hi << 16);
    const float hb = __uint_as_float(hi & 0xffff0000u);
    lo = pk2(a - ha, b - hb);                    // residual: split self-corrects
}
__device__ inline U4 packrow(const float* bl) {
    U4 r;
    r.u = make_uint4(pk2(bl[0], bl[1]), pk2(bl[2], bl[3]),
                     pk2(bl[4], bl[5]), pk2(bl[6], bl[7]));
    return r;
}

// ---- assign: 32 blocks x 256 thr (4 waves); wave w assigns 16 rows via
// 3-pass split-bf16 MFMA (hh, hl, lh; ll ~2^-18 dropped). Verified R11-R13.
__global__ __launch_bounds__(256) void assign_k(const float* __restrict__ x,
                                                const float* __restrict__ c,
                                                int* __restrict__ idx) {
    __shared__ int4 Bh[16 * 64];         // 16 KB: split(C^T) hi frags
    __shared__ int4 Bl[16 * 64];         // 16 KB: lo frags
    __shared__ float cc_s[KK];

    const int tid = threadIdx.x;
    const int w = tid >> 6, l = tid & 63;
    const int r16 = l & 15, g = l >> 4;
    const int r0 = blockIdx.x * 64;      // 64 rows per block

    // stage B = split(C^T): col=r16 is cluster, k-dim = s*32+g*8+j
    #pragma unroll
    for (int ss = 0; ss < 4; ++ss) {
        const int s = ss * 4 + w;
        const int c0 = s * 32 + g * 8;
        const float4 ca = *(const float4*)(c + (size_t)r16 * DD + c0);
        const float4 cb = *(const float4*)(c + (size_t)r16 * DD + c0 + 4);
        U4 H, L;
        split2(ca.x, ca.y, H.u.x, L.u.x);
        split2(ca.z, ca.w, H.u.y, L.u.y);
        split2(cb.x, cb.y, H.u.z, L.u.z);
        split2(cb.z, cb.w, H.u.w, L.u.w);
        Bh[s * 64 + l] = H.i;
        Bl[s * 64 + l] = L.i;
    }
    // cc[k] = sum_d c[k][d]^2 (k=tid>>4, 16 threads x 32 dims each)
    {
        const int k = tid >> 4, part = tid & 15;
        const float* cp = c + (size_t)k * DD + part * 32;
        float v = 0.f;
        #pragma unroll
        for (int q = 0; q < 8; ++q) {
            const float4 cv = *(const float4*)(cp + q * 4);
            v += cv.x * cv.x + cv.y * cv.y + cv.z * cv.z + cv.w * cv.w;
        }
        #pragma unroll
        for (int off = 1; off < 16; off <<= 1) v += __shfl_xor(v, off, 64);
        if (part == 0) cc_s[k] = v;
    }
    __syncthreads();

    // wave w: rows r0+w*16+r16; A-frags in registers; 3-pass MFMA chain
    const int grow = r0 + (w << 4) + r16;
    f4v acc = {0.f, 0.f, 0.f, 0.f};
    #pragma unroll 4
    for (int s = 0; s < 16; ++s) {
        const int c0 = s * 32 + g * 8;
        const float4 xa = *(const float4*)(x + (size_t)grow * DD + c0);
        const float4 xb = *(const float4*)(x + (size_t)grow * DD + c0 + 4);
        U4 ah, al;
        split2(xa.x, xa.y, ah.u.x, al.u.x);
        split2(xa.z, xa.w, ah.u.y, al.u.y);
        split2(xb.x, xb.y, ah.u.z, al.u.z);
        split2(xb.z, xb.w, ah.u.w, al.u.w);
        U4 bh, bl2;
        bh.i  = Bh[s * 64 + l];
        bl2.i = Bl[s * 64 + l];
        acc = __builtin_amdgcn_mfma_f32_16x16x32_bf16(ah.v, bh.v, acc, 0, 0, 0);
        acc = __builtin_amdgcn_mfma_f32_16x16x32_bf16(ah.v, bl2.v, acc, 0, 0, 0);
        acc = __builtin_amdgcn_mfma_f32_16x16x32_bf16(al.v, bh.v, acc, 0, 0, 0);
    }
    // D: col=r16 (cluster), row=4g+rr; argmin over 16 lanes, first-min ties
    const float ccv = cc_s[r16];
    #pragma unroll
    for (int rr = 0; rr < 4; ++rr) {
        float v = ccv - 2.0f * acc[rr];
        int k = r16;
        #pragma unroll
        for (int off = 1; off < 16; off <<= 1) {
            const float v2 = __shfl_xor(v, off, 64);
            const int k2 = __shfl_xor(k, off, 64);
            if (v2 < v || (v2 == v && k2 < k)) { v = v2; k = k2; }
        }
        if (r16 == 0) idx[r0 + (w << 4) + g * 4 + rr] = k;
    }
}

// ---- ae_k: byte-identical to R8 (passed, 27.8us) ----
__global__ __launch_bounds__(512) void ae_k(const float* __restrict__ x,
                                            const float* __restrict__ c,
                                            const float* __restrict__ encW,
                                            const float* __restrict__ encB,
                                            const float* __restrict__ decW,
                                            const float* __restrict__ decB,
                                            const int* __restrict__ idx,
                                            float* __restrict__ out) {
    __shared__ int4 frag[2048];          // 32 KB: enc A / dec A frags
    __shared__ ushort hist2[KK][512];    // 16 KB: transposed hist (2-way max)
    __shared__ float e_s[16][132];       // 8.25 KB
    __shared__ int rs_s[16];
    __shared__ ushort cnt_s[KK];
    __shared__ ushort tb_s[KK + 1];

    const int tid = threadIdx.x;
    const int b = blockIdx.x;
    const int w = tid >> 6, l = tid & 63;
    const int r16 = l & 15, g = l >> 4;

    // ---- phase 0: per-thread cluster counts, transposed layout ----
    const int4 my = *reinterpret_cast<const int4*>(idx + tid * 4);
    if (tid < 16) rs_s[tid] = -1;
    #pragma unroll
    for (int k = 0; k < KK; ++k) {
        hist2[k][tid] = (ushort)((my.x == k) + (my.y == k)
                               + (my.z == k) + (my.w == k));
    }
    __syncthreads();

    // wave w scans clusters 2w, 2w+1 over thread-order (lane l owns t=8l..8l+7)
    #pragma unroll
    for (int kk = 0; kk < 2; ++kk) {
        const int k = w * 2 + kk;
        int v[8], s = 0;
        #pragma unroll
        for (int i = 0; i < 8; ++i) { v[i] = hist2[k][l * 8 + i]; s += v[i]; }
        int sc = s;
        #pragma unroll
        for (int off = 1; off < 64; off <<= 1) {
            const int u = __shfl_up(sc, off, 64);
            if (l >= off) sc += u;
        }
        int e = sc - s;                  // exclusive start for t = 8l
        #pragma unroll
        for (int i = 0; i < 8; ++i) { hist2[k][l * 8 + i] = (ushort)e; e += v[i]; }
        if (l == 63) cnt_s[k] = (ushort)sc;
    }
    __syncthreads();
    if (tid == 0) {
        int ta = 0;
        for (int k = 0; k < KK; ++k) { tb_s[k] = (ushort)ta; ta += (cnt_s[k] + 15) >> 4; }
        tb_s[KK] = (ushort)ta;
    }
    __syncthreads();
    if (b >= (int)tb_s[KK]) return;      // uniform exit
    int km = 0;
    #pragma unroll
    for (int kk = 1; kk < KK; ++kk) if (b >= (int)tb_s[kk]) km = kk;
    const int base16 = (b - tb_s[km]) * 16;

    {   // scatter: my rows of cluster km whose rank lands in this tile
        int rank = hist2[km][tid];
        const int rv[4] = {my.x, my.y, my.z, my.w};
        #pragma unroll
        for (int i = 0; i < 4; ++i) {
            if (rv[i] == km) {
                if (rank >= base16 && rank < base16 + 16)
                    rs_s[rank - base16] = tid * 4 + i;
                rank++;
            }
        }
    }
    __syncthreads();

    // ---- issue enc weight batch 0 (s=0..7): 64 independent loads ----
    const float* Wp = encW + (size_t)km * DD * HH + w * 16 + r16;
    float bl0[8][8];
    #pragma unroll
    for (int s = 0; s < 8; ++s)
        #pragma unroll
        for (int j = 0; j < 8; ++j)
            bl0[s][j] = Wp[(size_t)(s * 32 + g * 8 + j) * HH];

    // ---- stage enc A = bf16split(x[row]-c[km]) in frag layout (2 slots/thr) ----
    int4* Ah = frag;                     // [16 ksteps][64 lanes]
    int4* Al = frag + 1024;
    {
        const int grow = rs_s[r16];
        const int s0 = tid >> 6;
        #pragma unroll
        for (int ss = 0; ss < 2; ++ss) {
            const int s = s0 + ss * 8;
            const int c0 = s * 32 + g * 8;
            float xv[8] = {0.f, 0.f, 0.f, 0.f, 0.f, 0.f, 0.f, 0.f};
            if (grow >= 0) {
                const float4 xa = *(const float4*)(x + (size_t)grow * DD + c0);
                const float4 xb = *(const float4*)(x + (size_t)grow * DD + c0 + 4);
                const float4 ca = *(const float4*)(c + (size_t)km * DD + c0);
                const float4 cb = *(const float4*)(c + (size_t)km * DD + c0 + 4);
                xv[0] = xa.x - ca.x; xv[1] = xa.y - ca.y;
                xv[2] = xa.z - ca.z; xv[3] = xa.w - ca.w;
                xv[4] = xb.x - cb.x; xv[5] = xb.y - cb.y;
                xv[6] = xb.z - cb.z; xv[7] = xb.w - cb.w;
            }
            U4 H, L;
            split2(xv[0], xv[1], H.u.x, L.u.x);
            split2(xv[2], xv[3], H.u.y, L.u.y);
            split2(xv[4], xv[5], H.u.z, L.u.z);
            split2(xv[6], xv[7], H.u.w, L.u.w);
            Ah[s * 64 + l] = H.i;        // lane-linear: conflict-free
            Al[s * 64 + l] = L.i;
        }
    }
    __syncthreads();

    // ---- enc MFMA: wave w owns h-cols [16w,16w+16), K=512, 2 batches ----
    f4v aH = {0.f, 0.f, 0.f, 0.f}, aL = {0.f, 0.f, 0.f, 0.f};
    {
        U4 bf0[8];
        #pragma unroll
        for (int s = 0; s < 8; ++s) bf0[s] = packrow(bl0[s]);   // waits batch 0

        float bl1[8][8];                 // issue batch 1 before MFMA batch 0
        #pragma unroll
        for (int s = 0; s < 8; ++s)
            #pragma unroll
            for (int j = 0; j < 8; ++j)
                bl1[s][j] = Wp[(size_t)((s + 8) * 32 + g * 8 + j) * HH];

        #pragma unroll
        for (int s = 0; s < 8; ++s) {
            U4 ah, al;
            ah.i = Ah[s * 64 + l];
            al.i = Al[s * 64 + l];
            aH = __builtin_amdgcn_mfma_f32_16x16x32_bf16(ah.v, bf0[s].v, aH, 0, 0, 0);
            aL = __builtin_amdgcn_mfma_f32_16x16x32_bf16(al.v, bf0[s].v, aL, 0, 0, 0);
        }
        U4 bf1[8];
        #pragma unroll
        for (int s = 0; s < 8; ++s) bf1[s] = packrow(bl1[s]);   // waits batch 1
        #pragma unroll
        for (int s = 8; s < 16; ++s) {
            U4 ah, al;
            ah.i = Ah[s * 64 + l];
            al.i = Al[s * 64 + l];
            aH = __builtin_amdgcn_mfma_f32_16x16x32_bf16(ah.v, bf1[s - 8].v, aH, 0, 0, 0);
            aL = __builtin_amdgcn_mfma_f32_16x16x32_bf16(al.v, bf1[s - 8].v, aL, 0, 0, 0);
        }
        const float bias = encB[km * HH + w * 16 + r16];
        #pragma unroll
        for (int rr = 0; rr < 4; ++rr)
            e_s[g * 4 + rr][w * 16 + r16] = fmaxf(aH[rr] + aL[rr] + bias, 0.f);
    }

    // ---- issue dec weight batch 0 (s=0..1, f=0..3) during e-staging ----
    const float* Vp = decW + (size_t)km * HH * DD + w * 64 + r16;
    float cl0[8][8];                     // p = s*4+f
    #pragma unroll
    for (int p = 0; p < 8; ++p)
        #pragma unroll
        for (int j = 0; j < 8; ++j)
            cl0[p][j] = Vp[(size_t)((p >> 2) * 32 + g * 8 + j) * DD + (p & 3) * 16];

    __syncthreads();

    // ---- stage dec A = bf16split(e) in frag layout (256 threads, 1 slot) ----
    int4* Dh = frag;                     // [4 ksteps][64 lanes] (reuse enc bufs)
    int4* Dl = frag + 256;
    if (tid < 256) {
        const int s = tid >> 6, ll = tid & 63;
        const int c0 = s * 32 + (ll >> 4) * 8;
        const float4 ea = *(const float4*)&e_s[ll & 15][c0];
        const float4 eb = *(const float4*)&e_s[ll & 15][c0 + 4];
        U4 H, L;
        split2(ea.x, ea.y, H.u.x, L.u.x);
        split2(ea.z, ea.w, H.u.y, L.u.y);
        split2(eb.x, eb.y, H.u.z, L.u.z);
        split2(eb.z, eb.w, H.u.w, L.u.w);
        Dh[s * 64 + ll] = H.i;
        Dl[s * 64 + ll] = L.i;
    }
    __syncthreads();

    // ---- dec MFMA: wave w owns d-cols [64w,64w+64) = 4 frags, K=128 ----
    f4v dH[4], dL[4];
    #pragma unroll
    for (int f = 0; f < 4; ++f) { dH[f] = (f4v){0.f,0.f,0.f,0.f}; dL[f] = (f4v){0.f,0.f,0.f,0.f}; }
    {
        U4 cf0[8];
        #pragma unroll
        for (int p = 0; p < 8; ++p) cf0[p] = packrow(cl0[p]);   // waits batch 0

        float cl1[8][8];                 // issue batch 1 (s=2..3) before MFMAs
        #pragma unroll
        for (int p = 0; p < 8; ++p)
            #pragma unroll
            for (int j = 0; j < 8; ++j)
                cl1[p][j] = Vp[(size_t)(((p >> 2) + 2) * 32 + g * 8 + j) * DD + (p & 3) * 16];

        #pragma unroll
        for (int s = 0; s < 2; ++s) {
            U4 ah, al;
            ah.i = Dh[s * 64 + l];
            al.i = Dl[s * 64 + l];
            #pragma unroll
            for (int f = 0; f < 4; ++f) {
                dH[f] = __builtin_amdgcn_mfma_f32_16x16x32_bf16(ah.v, cf0[s * 4 + f].v, dH[f], 0, 0, 0);
                dL[f] = __builtin_amdgcn_mfma_f32_16x16x32_bf16(al.v, cf0[s * 4 + f].v, dL[f], 0, 0, 0);
            }
        }
        U4 cf1[8];
        #pragma unroll
        for (int p = 0; p < 8; ++p) cf1[p] = packrow(cl1[p]);   // waits batch 1
        #pragma unroll
        for (int s = 2; s < 4; ++s) {
            U4 ah, al;
            ah.i = Dh[s * 64 + l];
            al.i = Dl[s * 64 + l];
            #pragma unroll
            for (int f = 0; f < 4; ++f) {
                dH[f] = __builtin_amdgcn_mfma_f32_16x16x32_bf16(ah.v, cf1[(s - 2) * 4 + f].v, dH[f], 0, 0, 0);
                dL[f] = __builtin_amdgcn_mfma_f32_16x16x32_bf16(al.v, cf1[(s - 2) * 4 + f].v, dL[f], 0, 0, 0);
            }
        }
    }
    // ---- epilogue: + bias -> out ----
    #pragma unroll
    for (int f = 0; f < 4; ++f) {
        const int d = w * 64 + f * 16 + r16;
        const float db = decB[km * DD + d];
        #pragma unroll
        for (int rr = 0; rr < 4; ++rr) {
            const int grow = rs_s[g * 4 + rr];
            if (grow >= 0)
                out[(size_t)grow * DD + d] = dH[f][rr] + dL[f][rr] + db;
        }
    }
}

extern "C" void kernel_launch(void* const* d_in, const int* in_sizes, int n_in,
                              void* d_out, int out_size, void* d_ws, size_t ws_size,
                              hipStream_t stream) {
    const float* x       = (const float*)d_in[0];
    const float* centers = (const float*)d_in[1];
    const float* enc_W   = (const float*)d_in[2];
    const float* enc_b   = (const float*)d_in[3];
    const float* dec_W   = (const float*)d_in[4];
    const float* dec_b   = (const float*)d_in[5];
    float* out = (float*)d_out;
    int* idx = (int*)d_ws;               // 2048 ints, rewritten every call

    assign_k<<<BB / 64, 256, 0, stream>>>(x, centers, idx);
    ae_k<<<MAXTILES, 512, 0, stream>>>(x, centers, enc_W, enc_b, dec_W, dec_b,
                                       idx, out);
}